// Round 1
// baseline (685.256 us; speedup 1.0000x reference)
//
#include <hip/hip_runtime.h>

// SimpleGRU scan: B=2048 seqs, T=2048 steps, H=32, O=2, fp32.
// Mapping: 32 lanes per batch (lane j owns gate rows j, j+32, j+64 of w_hh,
// 96 weights in VGPRs), 2 batches per wave, h state in LDS (broadcast reads).
// Sequential T-scan; per step: 8x ds_read_b128 (h bcast) + 96 v_fmac + HW
// exp/rcp activations + 1 ds_write. Within-wave LDS RAW relies on in-order DS
// processing; wave_barrier() pins compiler ordering (no s_barrier needed).

__device__ __forceinline__ float sigmoid_fast(float s) {
    // 1/(1+exp(-s)) via v_exp_f32 (exp2) + v_rcp_f32
    float e = __builtin_amdgcn_exp2f(s * -1.44269504088896340736f);
    return __builtin_amdgcn_rcpf(1.0f + e);
}

__device__ __forceinline__ float tanh_fast(float u) {
    // tanh(u) = 1 - 2/(1+exp(2u)); robust at both tails in fp32
    float e = __builtin_amdgcn_exp2f(u * 2.88539008177792681472f);
    float r = __builtin_amdgcn_rcpf(1.0f + e);
    return fmaf(-2.0f, r, 1.0f);
}

__global__ __launch_bounds__(64, 1)
void gru_scan_kernel(const float* __restrict__ x,      // [B,T]
                     const float* __restrict__ w_ih,   // [96,1]
                     const float* __restrict__ w_hh,   // [96,32]
                     const float* __restrict__ b_ih,   // [96]
                     const float* __restrict__ b_hh,   // [96]
                     const float* __restrict__ head_w, // [2,32]
                     const float* __restrict__ head_b, // [2]
                     float* __restrict__ out,          // [B,2]
                     int T)
{
    const int tid = (int)threadIdx.x;
    const int g   = tid >> 5;   // batch slot within wave (0,1)
    const int j   = tid & 31;   // gate lane / hidden index
    const int b   = (int)blockIdx.x * 2 + g;

    // h_s padded to 36 so group 1's reads land on different banks (group 0:
    // banks 0..3 for b128, group 1: banks 4..7) — conflict-free broadcast.
    __shared__ __align__(16) float h_s[2][36];
    __shared__ __align__(16) float x_s[2][2][32];  // [group][buf][step]

    // --- per-lane recurrent weights: rows j (r), 32+j (z), 64+j (n) ---
    float wr[32], wz[32], wn[32];
    {
        const float4* wr4 = (const float4*)(w_hh + (j     ) * 32);
        const float4* wz4 = (const float4*)(w_hh + (32 + j) * 32);
        const float4* wn4 = (const float4*)(w_hh + (64 + j) * 32);
#pragma unroll
        for (int q = 0; q < 8; ++q) {
            float4 a = wr4[q];
            wr[4*q+0]=a.x; wr[4*q+1]=a.y; wr[4*q+2]=a.z; wr[4*q+3]=a.w;
            float4 c = wz4[q];
            wz[4*q+0]=c.x; wz[4*q+1]=c.y; wz[4*q+2]=c.z; wz[4*q+3]=c.w;
            float4 d = wn4[q];
            wn[4*q+0]=d.x; wn[4*q+1]=d.y; wn[4*q+2]=d.z; wn[4*q+3]=d.w;
        }
    }
    const float wihr = w_ih[j];
    const float wihz = w_ih[32 + j];
    const float wihn = w_ih[64 + j];
    const float br   = b_ih[j]      + b_hh[j];       // r bias (combined)
    const float bz   = b_ih[32 + j] + b_hh[32 + j];  // z bias (combined)
    const float bni  = b_ih[64 + j];                 // n input-side bias
    const float bnh  = b_hh[64 + j];                 // n hidden-side bias

    const float* xrow   = x + (size_t)b * (size_t)T;
    const int    nchunk = T >> 5;   // T multiple of 32 (T=2048)

    float h = 0.0f;
    h_s[g][j]    = 0.0f;
    x_s[g][0][j] = xrow[j];                                // chunk 0
    float xnext  = (nchunk > 1) ? xrow[32 + j] : 0.0f;     // prefetch chunk 1
    __builtin_amdgcn_wave_barrier();

    for (int c = 0; c < nchunk; ++c) {
        const int buf = c & 1;
        const float* xs = &x_s[g][buf][0];
#pragma unroll 2
        for (int s = 0; s < 32; ++s) {
            const float xv = xs[s];                 // broadcast LDS read
            float racc = br, zacc = bz, nacc = bnh; // 3 indep FMA chains
            const float4* h4 = (const float4*)(&h_s[g][0]);
#pragma unroll
            for (int q = 0; q < 8; ++q) {
                const float4 hq = h4[q];            // ds_read_b128 broadcast
                racc = fmaf(hq.x, wr[4*q+0], racc);
                zacc = fmaf(hq.x, wz[4*q+0], zacc);
                nacc = fmaf(hq.x, wn[4*q+0], nacc);
                racc = fmaf(hq.y, wr[4*q+1], racc);
                zacc = fmaf(hq.y, wz[4*q+1], zacc);
                nacc = fmaf(hq.y, wn[4*q+1], nacc);
                racc = fmaf(hq.z, wr[4*q+2], racc);
                zacc = fmaf(hq.z, wz[4*q+2], zacc);
                nacc = fmaf(hq.z, wn[4*q+2], nacc);
                racc = fmaf(hq.w, wr[4*q+3], racc);
                zacc = fmaf(hq.w, wz[4*q+3], zacc);
                nacc = fmaf(hq.w, wn[4*q+3], nacc);
            }
            racc = fmaf(xv, wihr, racc);
            zacc = fmaf(xv, wihz, zacc);
            const float xn = fmaf(xv, wihn, bni);
            const float r  = sigmoid_fast(racc);
            const float z  = sigmoid_fast(zacc);
            const float n  = tanh_fast(fmaf(r, nacc, xn));
            h = fmaf(z, h - n, n);                  // (1-z)*n + z*h
            __builtin_amdgcn_wave_barrier();
            h_s[g][j] = h;                          // publish for next step
            __builtin_amdgcn_wave_barrier();        // in-order DS ⇒ RAW safe
        }
        if (c + 1 < nchunk) {
            x_s[g][1 - buf][j] = xnext;             // stage next chunk
            if (c + 2 < nchunk) xnext = xrow[(c + 2) * 32 + j];
            __builtin_amdgcn_wave_barrier();
        }
    }

    // --- head: out[b,o] = head_b[o] + sum_k h[k]*head_w[o,k], o in {0,1} ---
    __builtin_amdgcn_wave_barrier();
    if (j < 2) {
        float acc = head_b[j];
        const float* hw = head_w + j * 32;
#pragma unroll
        for (int k = 0; k < 32; ++k) acc = fmaf(h_s[g][k], hw[k], acc);
        out[b * 2 + j] = acc;
    }
}

extern "C" void kernel_launch(void* const* d_in, const int* in_sizes, int n_in,
                              void* d_out, int out_size, void* d_ws, size_t ws_size,
                              hipStream_t stream) {
    const float* x      = (const float*)d_in[0];
    const float* w_ih   = (const float*)d_in[1];
    const float* w_hh   = (const float*)d_in[2];
    const float* b_ih   = (const float*)d_in[3];
    const float* b_hh   = (const float*)d_in[4];
    const float* head_w = (const float*)d_in[5];
    const float* head_b = (const float*)d_in[6];
    float* out = (float*)d_out;

    const int B = out_size / 2;          // O = 2
    const int T = in_sizes[0] / B;       // x is [B,T]

    dim3 grid(B / 2), block(64);
    hipLaunchKernelGGL(gru_scan_kernel, grid, block, 0, stream,
                       x, w_ih, w_hh, b_ih, b_hh, head_w, head_b, out, T);
}